// Round 11
// baseline (2181.249 us; speedup 1.0000x reference)
//
#include <hip/hip_runtime.h>
#include <math.h>

#define BATCH   512
#define TSTEPS  3600
#define H       64
#define XCHUNK  8
#define NCHUNK  (TSTEPS / XCHUNK)   // 450
#define CLASSES 5

typedef _Float16 h2 __attribute__((ext_vector_type(2)));

__device__ __forceinline__ h2 bc_h2(unsigned int v) {
    return __builtin_bit_cast(h2, v);
}

__device__ __forceinline__ float fast_sigmoid(float x) {
    float e = __expf(-x);                 // |x| <= ~9 by construction
    return __builtin_amdgcn_rcpf(1.0f + e);
}
__device__ __forceinline__ float fast_tanh(float x) {
    float e = __expf(2.0f * x);           // |2x| <= ~18, no overflow
    return (e - 1.0f) * __builtin_amdgcn_rcpf(e + 1.0f);
}

// TWO BATCHES PER WAVE (256 blocks x 1 wave). R10's counters: issue ~270
// cyc/step vs wall ~818 -> ~550 cyc of per-step stall (LDS write->read RT
// ~170 + serial sigmoid/tanh tail ~130 + waitcnt overhead). With 512
// batches on 1024 SIMDs the HW cannot co-schedule a second wave, so we
// software-interleave two INDEPENDENT chains (batches 2b, 2b+1) in one
// wave. Both share the same per-lane weight rows -> weights stay 96 VGPRs.
// B's dot2 stream issues inside A's stalls and vice versa; one LDS RT
// exposure per 2 steps. Dot inputs f16 (threshold 4.6e-3, we run ~1e-3):
// h published as f16, read as 8 uniform ds_read_b128/batch, each dword a
// native v_dot2_f32_f16 operand. TBAA fix from R10 kept: asm memory
// clobber pins the f16-store / uint4-load order.
__global__ __launch_bounds__(64, 1) void gru_dot2x2_kernel(
    const float* __restrict__ x,      // [B, T, 1]
    const float* __restrict__ w_ih,   // [192, 1]
    const float* __restrict__ w_hh,   // [192, 64]
    const float* __restrict__ b_ih,   // [192]
    const float* __restrict__ b_hh,   // [192]
    const float* __restrict__ w_head, // [5, 64]
    const float* __restrict__ b_head, // [5]
    float* __restrict__ out)          // [B, 5]
{
    __shared__ __align__(16) _Float16 hlA[H];
    __shared__ __align__(16) _Float16 hlB[H];

    const int lane = threadIdx.x;    // block = 1 wave
    const int bA   = 2 * blockIdx.x;
    const int bB   = bA + 1;

    // --- recurrent weights as f16 pairs (shared by both batches) ---
    const float* r0 = w_hh + (0 * H + lane) * H;
    const float* r1 = w_hh + (1 * H + lane) * H;
    const float* r2 = w_hh + (2 * H + lane) * H;
    h2 wr[32], wz[32], wn[32];
#pragma unroll
    for (int u = 0; u < 32; ++u) {
        wr[u] = (h2){(_Float16)r0[2 * u], (_Float16)r0[2 * u + 1]};
        wz[u] = (h2){(_Float16)r1[2 * u], (_Float16)r1[2 * u + 1]};
        wn[u] = (h2){(_Float16)r2[2 * u], (_Float16)r2[2 * u + 1]};
    }

    const float wih_r = w_ih[lane], wih_z = w_ih[H + lane], wih_n = w_ih[2 * H + lane];
    const float bih_r = b_ih[lane], bih_z = b_ih[H + lane], bih_n = b_ih[2 * H + lane];
    const float bhh_r = b_hh[lane], bhh_z = b_hh[H + lane], bhh_n = b_hh[2 * H + lane];

    float hA = 0.0f, hB = 0.0f;
    const float* xbA = x + (size_t)bA * TSTEPS;
    const float* xbB = x + (size_t)bB * TSTEPS;

    // deterministic LDS start state (h0 = 0)
    hlA[lane] = (_Float16)0.0f;
    hlB[lane] = (_Float16)0.0f;
    __asm volatile("" ::: "memory");

    // x double-buffer per batch
    float xcA[XCHUNK], xnA[XCHUNK], xcB[XCHUNK], xnB[XCHUNK];
#pragma unroll
    for (int k = 0; k < XCHUNK; ++k) { xcA[k] = xbA[k]; xcB[k] = xbB[k]; }

    for (int tc = 0; tc < NCHUNK; ++tc) {
        const int noff = (tc + 1 < NCHUNK) ? (tc + 1) * XCHUNK : 0;
#pragma unroll
        for (int k = 0; k < XCHUNK; ++k) { xnA[k] = xbA[noff + k]; xnB[k] = xbB[noff + k]; }

#pragma unroll
        for (int tt = 0; tt < XCHUNK; ++tt) {
            // publish both h's, then broadcast-read both (one RT exposure)
            hlA[lane] = (_Float16)hA;
            hlB[lane] = (_Float16)hB;
            __asm volatile("" ::: "memory");

            const uint4* hpA = (const uint4*)hlA;
            const uint4* hpB = (const uint4*)hlB;
            const uint4 a0 = hpA[0], a1 = hpA[1], a2 = hpA[2], a3 = hpA[3];
            const uint4 a4 = hpA[4], a5 = hpA[5], a6 = hpA[6], a7 = hpA[7];
            const uint4 c0 = hpB[0], c1 = hpB[1], c2 = hpB[2], c3 = hpB[3];
            const uint4 c4 = hpB[4], c5 = hpB[5], c6 = hpB[6], c7 = hpB[7];

            float arA = bhh_r, azA = bhh_z, anA = bhh_n;
            float arB = bhh_r, azB = bhh_z, anB = bhh_n;

            // interleaved dual-batch dot stream: 6 dot2 per u, all
            // independent except the per-gate accumulator chains (depth 32)
#define RND2(u, PA, PB)                                                \
            arA = __builtin_amdgcn_fdot2(wr[u], (PA), arA, false);     \
            arB = __builtin_amdgcn_fdot2(wr[u], (PB), arB, false);     \
            azA = __builtin_amdgcn_fdot2(wz[u], (PA), azA, false);     \
            azB = __builtin_amdgcn_fdot2(wz[u], (PB), azB, false);     \
            anA = __builtin_amdgcn_fdot2(wn[u], (PA), anA, false);     \
            anB = __builtin_amdgcn_fdot2(wn[u], (PB), anB, false);

            RND2(0,  bc_h2(a0.x), bc_h2(c0.x)) RND2(1,  bc_h2(a0.y), bc_h2(c0.y))
            RND2(2,  bc_h2(a0.z), bc_h2(c0.z)) RND2(3,  bc_h2(a0.w), bc_h2(c0.w))
            RND2(4,  bc_h2(a1.x), bc_h2(c1.x)) RND2(5,  bc_h2(a1.y), bc_h2(c1.y))
            RND2(6,  bc_h2(a1.z), bc_h2(c1.z)) RND2(7,  bc_h2(a1.w), bc_h2(c1.w))
            RND2(8,  bc_h2(a2.x), bc_h2(c2.x)) RND2(9,  bc_h2(a2.y), bc_h2(c2.y))
            RND2(10, bc_h2(a2.z), bc_h2(c2.z)) RND2(11, bc_h2(a2.w), bc_h2(c2.w))
            RND2(12, bc_h2(a3.x), bc_h2(c3.x)) RND2(13, bc_h2(a3.y), bc_h2(c3.y))
            RND2(14, bc_h2(a3.z), bc_h2(c3.z)) RND2(15, bc_h2(a3.w), bc_h2(c3.w))
            RND2(16, bc_h2(a4.x), bc_h2(c4.x)) RND2(17, bc_h2(a4.y), bc_h2(c4.y))
            RND2(18, bc_h2(a4.z), bc_h2(c4.z)) RND2(19, bc_h2(a4.w), bc_h2(c4.w))
            RND2(20, bc_h2(a5.x), bc_h2(c5.x)) RND2(21, bc_h2(a5.y), bc_h2(c5.y))
            RND2(22, bc_h2(a5.z), bc_h2(c5.z)) RND2(23, bc_h2(a5.w), bc_h2(c5.w))
            RND2(24, bc_h2(a6.x), bc_h2(c6.x)) RND2(25, bc_h2(a6.y), bc_h2(c6.y))
            RND2(26, bc_h2(a6.z), bc_h2(c6.z)) RND2(27, bc_h2(a6.w), bc_h2(c6.w))
            RND2(28, bc_h2(a7.x), bc_h2(c7.x)) RND2(29, bc_h2(a7.y), bc_h2(c7.y))
            RND2(30, bc_h2(a7.z), bc_h2(c7.z)) RND2(31, bc_h2(a7.w), bc_h2(c7.w))
#undef RND2

            // interleaved tails: A's transcendental latency hides under B's
            const float xtA = xcA[tt], xtB = xcB[tt];
            const float rA = fast_sigmoid(fmaf(xtA, wih_r, bih_r) + arA);
            const float rB = fast_sigmoid(fmaf(xtB, wih_r, bih_r) + arB);
            const float zA = fast_sigmoid(fmaf(xtA, wih_z, bih_z) + azA);
            const float zB = fast_sigmoid(fmaf(xtB, wih_z, bih_z) + azB);
            const float nA = fast_tanh(fmaf(xtA, wih_n, bih_n) + rA * anA);
            const float nB = fast_tanh(fmaf(xtB, wih_n, bih_n) + rB * anB);
            hA = fmaf(zA, hA - nA, nA);
            hB = fmaf(zB, hB - nB, nB);
        }

#pragma unroll
        for (int k = 0; k < XCHUNK; ++k) { xcA[k] = xnA[k]; xcB[k] = xnB[k]; }
    }

    // ---- head for both batches ----
#pragma unroll
    for (int cc = 0; cc < CLASSES; ++cc) {
        float vA = hA * w_head[cc * H + lane];
        float vB = hB * w_head[cc * H + lane];
#pragma unroll
        for (int off = 32; off > 0; off >>= 1) {
            vA += __shfl_down(vA, off, 64);
            vB += __shfl_down(vB, off, 64);
        }
        if (lane == 0) {
            out[bA * CLASSES + cc] = vA + b_head[cc];
            out[bB * CLASSES + cc] = vB + b_head[cc];
        }
    }
}

extern "C" void kernel_launch(void* const* d_in, const int* in_sizes, int n_in,
                              void* d_out, int out_size, void* d_ws, size_t ws_size,
                              hipStream_t stream) {
    const float* x      = (const float*)d_in[0];
    const float* w_ih   = (const float*)d_in[1];
    const float* w_hh   = (const float*)d_in[2];
    const float* b_ih   = (const float*)d_in[3];
    const float* b_hh   = (const float*)d_in[4];
    const float* w_head = (const float*)d_in[5];
    const float* b_head = (const float*)d_in[6];
    float* out = (float*)d_out;

    gru_dot2x2_kernel<<<BATCH / 2, 64, 0, stream>>>(x, w_ih, w_hh, b_ih, b_hh,
                                                    w_head, b_head, out);
}

// Round 12
// 1946.148 us; speedup vs baseline: 1.1208x; 1.1208x over previous
//
#include <hip/hip_runtime.h>
#include <math.h>

#define BATCH   512
#define TSTEPS  3600
#define H       64
#define XCHUNK  16
#define NCHUNK  (TSTEPS / XCHUNK)   // 225
#define CLASSES 5
#define WPB     8                   // waves per block -> 2 waves per SIMD

typedef _Float16 h2 __attribute__((ext_vector_type(2)));

__device__ __forceinline__ h2 bc_h2(unsigned int v) {
    return __builtin_bit_cast(h2, v);
}

__device__ __forceinline__ float fast_sigmoid(float x) {
    float e = __expf(-x);                 // |x| <= ~9 by construction
    return __builtin_amdgcn_rcpf(1.0f + e);
}
__device__ __forceinline__ float fast_tanh(float x) {
    float e = __expf(2.0f * x);           // |2x| <= ~18, no overflow
    return (e - 1.0f) * __builtin_amdgcn_rcpf(e + 1.0f);
}

// R10 per-wave structure (f16 dot2, LDS h-broadcast, TBAA clobber) with one
// placement change: 8 INDEPENDENT batch-waves per block. Waves of a block
// are distributed round-robin over the CU's 4 SIMDs -> 2 waves/SIMD. A lone
// wave issues ~1 VALU instr / 4 cyc (R6/R10 fit); two co-resident waves
// interleave into the 2-cyc pipe slots AND hide each other's LDS round-trip
// + transcendental tail. No cross-wave coupling: private hl slice per wave,
// no barriers. R11's failure mode (register spill from doubling per-wave
// live set) is structurally avoided: per-wave footprint identical to R10.
// Also: 6 dot-accumulator chains (was 3) so dependent v_dot2s sit >=6
// instrs apart - kills chain-latency stall even when issuing solo.
__global__ __launch_bounds__(WPB * 64, 1) void gru_dot2_w8_kernel(
    const float* __restrict__ x,      // [B, T, 1]
    const float* __restrict__ w_ih,   // [192, 1]
    const float* __restrict__ w_hh,   // [192, 64]
    const float* __restrict__ b_ih,   // [192]
    const float* __restrict__ b_hh,   // [192]
    const float* __restrict__ w_head, // [5, 64]
    const float* __restrict__ b_head, // [5]
    float* __restrict__ out)          // [B, 5]
{
    __shared__ __align__(16) _Float16 hl[WPB][H];

    const int tid  = threadIdx.x;
    const int wv   = tid >> 6;
    const int lane = tid & 63;
    const int b    = blockIdx.x * WPB + wv;

    _Float16* hlw = hl[wv];          // private per-wave h buffer

    // --- recurrent weights as f16 pairs: wg[u] = {row[2u], row[2u+1]} ---
    const float* r0 = w_hh + (0 * H + lane) * H;
    const float* r1 = w_hh + (1 * H + lane) * H;
    const float* r2 = w_hh + (2 * H + lane) * H;
    h2 wr[32], wz[32], wn[32];
#pragma unroll
    for (int u = 0; u < 32; ++u) {
        wr[u] = (h2){(_Float16)r0[2 * u], (_Float16)r0[2 * u + 1]};
        wz[u] = (h2){(_Float16)r1[2 * u], (_Float16)r1[2 * u + 1]};
        wn[u] = (h2){(_Float16)r2[2 * u], (_Float16)r2[2 * u + 1]};
    }

    const float wih_r = w_ih[lane], wih_z = w_ih[H + lane], wih_n = w_ih[2 * H + lane];
    const float bih_r = b_ih[lane], bih_z = b_ih[H + lane], bih_n = b_ih[2 * H + lane];
    const float bhh_r = b_hh[lane], bhh_z = b_hh[H + lane], bhh_n = b_hh[2 * H + lane];

    float h_reg = 0.0f;
    const float* xb = x + (size_t)b * TSTEPS;

    // deterministic LDS start state (h0 = 0)
    hlw[lane] = (_Float16)0.0f;
    __asm volatile("" ::: "memory");

    // x double-buffer: current chunk in xc, prefetch next into xn
    float xc[XCHUNK], xn[XCHUNK];
#pragma unroll
    for (int k = 0; k < XCHUNK; ++k) xc[k] = xb[k];

    for (int tc = 0; tc < NCHUNK; ++tc) {
        const float* nb = xb + ((tc + 1 < NCHUNK) ? (tc + 1) * XCHUNK : 0);
#pragma unroll
        for (int k = 0; k < XCHUNK; ++k) xn[k] = nb[k];

#pragma unroll
        for (int tt = 0; tt < XCHUNK; ++tt) {
            // publish h as f16; clobber pins store<->load order (TBAA fix)
            hlw[lane] = (_Float16)h_reg;
            __asm volatile("" ::: "memory");

            const uint4* hp = (const uint4*)hlw;  // wave-uniform broadcast
            const uint4 q0 = hp[0], q1 = hp[1], q2 = hp[2], q3 = hp[3];
            const uint4 q4 = hp[4], q5 = hp[5], q6 = hp[6], q7 = hp[7];

            // 6 accumulator chains: dependent dot2s >= 6 instrs apart
            float ar0 = bhh_r, az0 = bhh_z, an0 = bhh_n;
            float ar1 = 0.f,   az1 = 0.f,   an1 = 0.f;

#define RND(u, P)                                                       \
            ar0 = __builtin_amdgcn_fdot2(wr[u],     (P).x, ar0, false); \
            az0 = __builtin_amdgcn_fdot2(wz[u],     (P).x, az0, false); \
            an0 = __builtin_amdgcn_fdot2(wn[u],     (P).x, an0, false); \
            ar1 = __builtin_amdgcn_fdot2(wr[u + 1], (P).y, ar1, false); \
            az1 = __builtin_amdgcn_fdot2(wz[u + 1], (P).y, az1, false); \
            an1 = __builtin_amdgcn_fdot2(wn[u + 1], (P).y, an1, false);

            struct pp { h2 x, y; };
#define PAIR(qa, qb) (pp){bc_h2(qa), bc_h2(qb)}
            RND(0,  PAIR(q0.x, q0.y)) RND(2,  PAIR(q0.z, q0.w))
            RND(4,  PAIR(q1.x, q1.y)) RND(6,  PAIR(q1.z, q1.w))
            RND(8,  PAIR(q2.x, q2.y)) RND(10, PAIR(q2.z, q2.w))
            RND(12, PAIR(q3.x, q3.y)) RND(14, PAIR(q3.z, q3.w))
            RND(16, PAIR(q4.x, q4.y)) RND(18, PAIR(q4.z, q4.w))
            RND(20, PAIR(q5.x, q5.y)) RND(22, PAIR(q5.z, q5.w))
            RND(24, PAIR(q6.x, q6.y)) RND(26, PAIR(q6.z, q6.w))
            RND(28, PAIR(q7.x, q7.y)) RND(30, PAIR(q7.z, q7.w))
#undef PAIR
#undef RND

            const float ar = ar0 + ar1;
            const float az = az0 + az1;
            const float an = an0 + an1;

            const float xt = xc[tt];
            const float r = fast_sigmoid(fmaf(xt, wih_r, bih_r) + ar);
            const float z = fast_sigmoid(fmaf(xt, wih_z, bih_z) + az);
            const float n = fast_tanh(fmaf(xt, wih_n, bih_n) + r * an);
            h_reg = fmaf(z, h_reg - n, n);   // (1-z)*n + z*h
        }

#pragma unroll
        for (int k = 0; k < XCHUNK; ++k) xc[k] = xn[k];
    }

    // ---- head: out[b][c] = w_head[c,:] . h + b_head[c] ----
#pragma unroll
    for (int cc = 0; cc < CLASSES; ++cc) {
        float v = h_reg * w_head[cc * H + lane];
#pragma unroll
        for (int off = 32; off > 0; off >>= 1)
            v += __shfl_down(v, off, 64);
        if (lane == 0) out[b * CLASSES + cc] = v + b_head[cc];
    }
}

extern "C" void kernel_launch(void* const* d_in, const int* in_sizes, int n_in,
                              void* d_out, int out_size, void* d_ws, size_t ws_size,
                              hipStream_t stream) {
    const float* x      = (const float*)d_in[0];
    const float* w_ih   = (const float*)d_in[1];
    const float* w_hh   = (const float*)d_in[2];
    const float* b_ih   = (const float*)d_in[3];
    const float* b_hh   = (const float*)d_in[4];
    const float* w_head = (const float*)d_in[5];
    const float* b_head = (const float*)d_in[6];
    float* out = (float*)d_out;

    gru_dot2_w8_kernel<<<BATCH / WPB, WPB * 64, 0, stream>>>(
        x, w_ih, w_hh, b_ih, b_hh, w_head, b_head, out);
}

// Round 13
// 1089.084 us; speedup vs baseline: 2.0028x; 1.7870x over previous
//
#include <hip/hip_runtime.h>
#include <math.h>

#define BATCH   512
#define TSTEPS  3600
#define H       64
#define XCHUNK  16
#define NCHUNK  (TSTEPS / XCHUNK)   // 225
#define CLASSES 5

typedef _Float16 half8 __attribute__((ext_vector_type(8)));
typedef float    f32x4 __attribute__((ext_vector_type(4)));

__device__ __forceinline__ half8 bc_h8(uint4 v) {
    return __builtin_bit_cast(half8, v);
}

__device__ __forceinline__ float fast_sigmoid(float x) {
    float e = __expf(-x);                 // |x| <= ~9 by construction
    return __builtin_amdgcn_rcpf(1.0f + e);
}
__device__ __forceinline__ float fast_tanh(float x) {
    float e = __expf(2.0f * x);           // |2x| <= ~18, no overflow
    return (e - 1.0f) * __builtin_amdgcn_rcpf(e + 1.0f);
}

// ONE WAVE per batch, MFMA GEMV. R10's 818-cyc chain was dominated by 96
// v_dot2 at the solo-wave issue cadence (~4 cyc/instr) + LDS RT. Here the
// 12288-MAC matvec collapses into 24 v_mfma_f32_16x16x32_f16:
//   A[m][k] = h_k  (h replicated across rows -> A's m-mapping irrelevant;
//                   lane reads its k-octet {8q..8q+7} = 16B from LDS)
//   B[k][n] = W_hh[16t+n][k]  (n = lane&15; static, preloaded, AGPR-friendly)
//   D[row][col] = gh[16t+col]  (replicated over rows; col=lane&15 is the
//                   m89-verified mapping). k-order is consistent between A
//   (memory-ordered read) and B (same pack order), so k-permutation
//   conventions cancel. Lane L ends up holding gh for hidden index L
//   exactly (i = 16q + col = L): gate phase selects r/z/n tiles by q via
//   cndmask trees, tail identical to R10. Per-step DS: 1 write + 2 b128
//   reads (vs R10's 1+8). r-tiles issue first so r's sigmoid overlaps the
//   z/n MFMAs. Latency race: 512 serial chains; chain ~ RT + 24 MFMA + tail.
__global__ __launch_bounds__(64, 1) void gru_mfma_kernel(
    const float* __restrict__ x,      // [B, T, 1]
    const float* __restrict__ w_ih,   // [192, 1]
    const float* __restrict__ w_hh,   // [192, 64]
    const float* __restrict__ b_ih,   // [192]
    const float* __restrict__ b_hh,   // [192]
    const float* __restrict__ w_head, // [5, 64]
    const float* __restrict__ b_head, // [5]
    float* __restrict__ out)          // [B, 5]
{
    __shared__ __align__(16) _Float16 hl[H];

    const int lane = threadIdx.x;    // block = 1 wave
    const int b    = blockIdx.x;
    const int q    = lane >> 4;      // k-octet / row-tile selector
    const int col  = lane & 15;      // B n-index / D col

    // --- B fragments: W_hh tiles, f16, B[k=8q+j][n=col] = W[16t+col][32c+8q+j]
    half8 wB[12][2];
#pragma unroll
    for (int t = 0; t < 12; ++t) {
#pragma unroll
        for (int c = 0; c < 2; ++c) {
            const float* wr = w_hh + (16 * t + col) * H + 32 * c + 8 * q;
            half8 f;
#pragma unroll
            for (int j = 0; j < 8; ++j) f[j] = (_Float16)wr[j];
            wB[t][c] = f;
        }
    }

    // gate parameters for hidden index = lane
    const float wih_r = w_ih[lane], wih_z = w_ih[H + lane], wih_n = w_ih[2 * H + lane];
    const float bsr = b_ih[lane] + b_hh[lane];              // merged r bias
    const float bsz = b_ih[H + lane] + b_hh[H + lane];      // merged z bias
    const float bin = b_ih[2 * H + lane];                   // n: keep split,
    const float bhn = b_hh[2 * H + lane];                   // r multiplies bhh_n

    float h_reg = 0.0f;
    const float* xb = x + (size_t)b * TSTEPS;

    // deterministic LDS start state (h0 = 0)
    hl[lane] = (_Float16)0.0f;
    __asm volatile("" ::: "memory");

    const f32x4 Z = {0.f, 0.f, 0.f, 0.f};

    // x double-buffer
    float xc[XCHUNK], xn[XCHUNK];
#pragma unroll
    for (int k = 0; k < XCHUNK; ++k) xc[k] = xb[k];

    for (int tc = 0; tc < NCHUNK; ++tc) {
        const float* nb = xb + ((tc + 1 < NCHUNK) ? (tc + 1) * XCHUNK : 0);
#pragma unroll
        for (int k = 0; k < XCHUNK; ++k) xn[k] = nb[k];

#pragma unroll
        for (int tt = 0; tt < XCHUNK; ++tt) {
            // publish h as f16; clobber pins store<->load order (TBAA)
            hl[lane] = (_Float16)h_reg;
            __asm volatile("" ::: "memory");

            // A fragments: h k-octets, 16B each (wave-broadcast per quad)
            const uint4* hp = (const uint4*)hl;
            const half8 A0 = bc_h8(hp[q]);        // k = 8q..8q+7
            const half8 A1 = bc_h8(hp[4 + q]);    // k = 32+8q..32+8q+7

            const float xt = xc[tt];
            // input-projection terms: off the critical path
            const float ir = fmaf(xt, wih_r, bsr);
            const float iz = fmaf(xt, wih_z, bsz);
            const float in_ = fmaf(xt, wih_n, bin);

#define GEMV(t, d)                                                     \
            d = __builtin_amdgcn_mfma_f32_16x16x32_f16(A0, wB[t][0], Z, 0, 0, 0); \
            d = __builtin_amdgcn_mfma_f32_16x16x32_f16(A1, wB[t][1], d, 0, 0, 0);

            // ---- r tiles first: sigmoid overlaps the z/n MFMAs ----
            f32x4 d0, d1, d2, d3;
            GEMV(0, d0) GEMV(1, d1) GEMV(2, d2) GEMV(3, d3)
            const float ghr = (q < 2) ? (q == 0 ? d0[0] : d1[0])
                                      : (q == 2 ? d2[0] : d3[0]);
            const float r = fast_sigmoid(ir + ghr);

            f32x4 e0, e1, e2, e3;
            GEMV(4, e0) GEMV(5, e1) GEMV(6, e2) GEMV(7, e3)
            const float ghz = (q < 2) ? (q == 0 ? e0[0] : e1[0])
                                      : (q == 2 ? e2[0] : e3[0]);
            const float z = fast_sigmoid(iz + ghz);

            f32x4 g0, g1, g2, g3;
            GEMV(8, g0) GEMV(9, g1) GEMV(10, g2) GEMV(11, g3)
            const float ghn = (q < 2) ? (q == 0 ? g0[0] : g1[0])
                                      : (q == 2 ? g2[0] : g3[0]);
#undef GEMV

            const float n = fast_tanh(in_ + r * (ghn + bhn));
            h_reg = fmaf(z, h_reg - n, n);   // (1-z)*n + z*h
        }

#pragma unroll
        for (int k = 0; k < XCHUNK; ++k) xc[k] = xn[k];
    }

    // ---- head: out[b][c] = w_head[c,:] . h + b_head[c] ----
#pragma unroll
    for (int cc = 0; cc < CLASSES; ++cc) {
        float v = h_reg * w_head[cc * H + lane];
#pragma unroll
        for (int off = 32; off > 0; off >>= 1)
            v += __shfl_down(v, off, 64);
        if (lane == 0) out[b * CLASSES + cc] = v + b_head[cc];
    }
}

extern "C" void kernel_launch(void* const* d_in, const int* in_sizes, int n_in,
                              void* d_out, int out_size, void* d_ws, size_t ws_size,
                              hipStream_t stream) {
    const float* x      = (const float*)d_in[0];
    const float* w_ih   = (const float*)d_in[1];
    const float* w_hh   = (const float*)d_in[2];
    const float* b_ih   = (const float*)d_in[3];
    const float* b_hh   = (const float*)d_in[4];
    const float* w_head = (const float*)d_in[5];
    const float* b_head = (const float*)d_in[6];
    float* out = (float*)d_out;

    gru_mfma_kernel<<<BATCH, 64, 0, stream>>>(x, w_ih, w_hh, b_ih, b_hh,
                                              w_head, b_head, out);
}